// Round 3
// baseline (188.438 us; speedup 1.0000x reference)
//
#include <hip/hip_runtime.h>
#include <hip/hip_bf16.h>

#define C   336
#define CR  84
#define BB  256
#define HW  196           // 14*14
#define NKC 11            // ceil(336/32)
#define NNF 21            // 336/16
#define NBLK 784          // gemm/pack grid: 784 blocks x 4 waves = 3136 tiles

typedef __attribute__((ext_vector_type(8))) short bf16x8;
typedef __attribute__((ext_vector_type(4))) float f32x4;

__device__ __forceinline__ short f2bf(float f) {
    unsigned u = __builtin_bit_cast(unsigned, f);
    u += 0x7fffu + ((u >> 16) & 1u);   // round-to-nearest-even
    return (short)(u >> 16);
}

// ---------------------------------------------------------------- prep w53 -> bf16 frag-linear
// frag f = kc*21+nf; wbf[(f*64 + lane)*8 + j] = bf16(w53[o][c]),
// o = nf*16 + (lane&15), c = kc*32 + (lane>>4)*8 + j  (zero pad c>=336)
__global__ void prep_w(const float* __restrict__ w53, short* __restrict__ wbf) {
    const int f = blockIdx.x;           // 0..230
    const int kc = f / NNF, nf = f - kc * NNF;
    const int lane = threadIdx.x;
    const int o = nf * 16 + (lane & 15);
    const int cb = kc * 32 + (lane >> 4) * 8;
    short* dst = wbf + ((size_t)f * 64 + lane) * 8;
#pragma unroll
    for (int j = 0; j < 8; ++j) {
        const int c = cb + j;
        dst[j] = f2bf((c < C) ? w53[o * C + c] : 0.f);
    }
}

// ---------------------------------------------------------------- SE gate (block per batch, 384 thr)
__global__ void gate_kernel(const float* __restrict__ x160,
                            const float* __restrict__ w51, const float* __restrict__ b51,
                            const float* __restrict__ w52, const float* __restrict__ b52,
                            float* __restrict__ gate)
{
    __shared__ float s[C];
    __shared__ float red[C];
    __shared__ float h[CR];
    const int b = blockIdx.x, t = threadIdx.x;
    if (t < C) s[t] = x160[b * C + t];
    __syncthreads();
    if (t < C) {                       // layer 1: 84 outputs x 4 threads
        const int o = t >> 2, j = t & 3;
        float a = 0.f;
        const float* wr = w51 + o * C;
        for (int c = j; c < C; c += 4) a = fmaf(wr[c], s[c], a);
        red[t] = a;
    }
    __syncthreads();
    if (t < CR) {
        float a = red[4*t] + red[4*t+1] + red[4*t+2] + red[4*t+3] + b51[t];
        h[t] = fmaxf(a, 0.f);
    }
    __syncthreads();
    if (t < C) {                       // layer 2
        float a = b52[t];
        const float* wr = w52 + t * CR;
        for (int j = 0; j < CR; ++j) a = fmaf(wr[j], h[j], a);
        gate[b * C + t] = 1.f / (1.f + expf(-a));
    }
}

// ---------------------------------------------------------------- pack A = bf16(x159*gate), frag-linear
// apack[((t*11+kc)*64 + lane)*8 + j] = bf16(x159[bA][c][pA] * gate[bA][c])
// t = wave tile, mA = t*16 + (lane&15), c = kc*32 + (lane>>4)*8 + j
__global__ void pack_kernel(const float* __restrict__ x159, const float* __restrict__ gate,
                            short* __restrict__ apack)
{
    const int lane = threadIdx.x & 63;
    const int wid  = threadIdx.x >> 6;
    const int t    = blockIdx.x * 4 + wid;
    const int mA = t * 16 + (lane & 15);
    const int bA = mA / HW;
    const int pA = mA - bA * HW;
    const float* __restrict__ xrow = x159 + (size_t)bA * (C * HW) + pA;
    const float* __restrict__ grow = gate + bA * C;
    const int kg = lane >> 4;
    short* dst = apack + ((size_t)t * NKC * 64 + lane) * 8;
#pragma unroll
    for (int kc = 0; kc < NKC; ++kc) {
        const int cbase = kc * 32 + kg * 8;
        bf16x8 a;
#pragma unroll
        for (int j = 0; j < 8; ++j) {
            const int c = cbase + j;
            float v = 0.f;
            if (c < C) v = xrow[(size_t)c * HW] * grow[c];
            a[j] = f2bf(v);
        }
        *(bf16x8*)(dst + (size_t)kc * 512) = a;
    }
}

// ---------------------------------------------------------------- shared GEMM core (register MFMA)
__device__ __forceinline__ void gemm_core(const short* __restrict__ apack,
                                          const short* __restrict__ wbf,
                                          int t, int lane, f32x4 acc[NNF])
{
#pragma unroll
    for (int i = 0; i < NNF; ++i) acc[i] = f32x4{0.f, 0.f, 0.f, 0.f};
    const short* ap  = apack + ((size_t)t * NKC * 64 + lane) * 8;
    const short* wb0 = wbf + (size_t)lane * 8;
    bf16x8 a_cur = *(const bf16x8*)ap;
    for (int kc = 0; kc < NKC; ++kc) {
        bf16x8 a_nxt = a_cur;
        if (kc < NKC - 1) a_nxt = *(const bf16x8*)(ap + (size_t)(kc + 1) * 512);
        const short* wb = wb0 + (size_t)kc * NNF * 512;
#pragma unroll
        for (int nf = 0; nf < NNF; ++nf) {
            const bf16x8 bfrag = *(const bf16x8*)(wb + (size_t)nf * 512);
            acc[nf] = __builtin_amdgcn_mfma_f32_16x16x32_bf16(a_cur, bfrag, acc[nf], 0, 0, 0);
        }
        a_cur = a_nxt;
    }
}

// ---------------------------------------------------------------- pass 1: GEMM -> per-block channel partials
__global__ void gemm_stats(const short* __restrict__ apack, const short* __restrict__ wbf,
                           float* __restrict__ part)
{
    const int lane = threadIdx.x & 63;
    const int wid  = threadIdx.x >> 6;
    const int t    = blockIdx.x * 4 + wid;

    f32x4 acc[NNF];
    gemm_core(apack, wbf, t, lane, acc);

    __shared__ float lds_s[4][C];
    __shared__ float lds_q[4][C];
#pragma unroll
    for (int nf = 0; nf < NNF; ++nf) {
        float s = acc[nf][0] + acc[nf][1] + acc[nf][2] + acc[nf][3];
        float q = acc[nf][0]*acc[nf][0] + acc[nf][1]*acc[nf][1]
                + acc[nf][2]*acc[nf][2] + acc[nf][3]*acc[nf][3];
        s += __shfl_xor(s, 16); q += __shfl_xor(q, 16);
        s += __shfl_xor(s, 32); q += __shfl_xor(q, 32);
        if (lane < 16) { lds_s[wid][nf*16 + lane] = s; lds_q[wid][nf*16 + lane] = q; }
    }
    __syncthreads();
    for (int i = threadIdx.x; i < C; i += 256) {
        part[(size_t)blockIdx.x * (2*C) + 2*i]     = lds_s[0][i] + lds_s[1][i] + lds_s[2][i] + lds_s[3][i];
        part[(size_t)blockIdx.x * (2*C) + 2*i + 1] = lds_q[0][i] + lds_q[1][i] + lds_q[2][i] + lds_q[3][i];
    }
}

// ---------------------------------------------------------------- fold partials -> per-channel (a,b)
__global__ void stats_final_a(const float* __restrict__ part,
                              const float* __restrict__ gamma, const float* __restrict__ beta,
                              float* __restrict__ ab)
{
    const int o = blockIdx.x;          // 0..335
    const int lane = threadIdx.x;      // 0..63
    float s = 0.f, q = 0.f;
    for (int i = lane; i < NBLK; i += 64) {
        s += part[(size_t)i * (2*C) + 2*o];
        q += part[(size_t)i * (2*C) + 2*o + 1];
    }
#pragma unroll
    for (int d = 1; d < 64; d <<= 1) { s += __shfl_xor(s, d); q += __shfl_xor(q, d); }
    if (lane == 0) {
        const float invN = 1.f / (float)(BB * HW);
        const float mean = s * invN;
        const float var  = fmaxf(q * invN - mean * mean, 0.f);
        const float rstd = rsqrtf(var + 1e-5f);
        const float a = rstd * gamma[o];
        ab[2*o]     = a;
        ab[2*o + 1] = beta[o] - mean * a;
    }
}

// ---------------------------------------------------------------- pass 2: GEMM -> normalize -> out
__global__ void gemm_norm(const short* __restrict__ apack, const short* __restrict__ wbf,
                          const float* __restrict__ ab, float* __restrict__ out)
{
    __shared__ float s_ab[2*C];
    for (int i = threadIdx.x; i < 2*C; i += 256) s_ab[i] = ab[i];
    __syncthreads();

    const int lane = threadIdx.x & 63;
    const int wid  = threadIdx.x >> 6;
    const int t    = blockIdx.x * 4 + wid;

    f32x4 acc[NNF];
    gemm_core(apack, wbf, t, lane, acc);

    const int r  = lane & 15;
    const int kg = lane >> 4;
    const int mC = t * 16 + kg * 4;
    const int bC = mC / HW;
    const int pC = mC - bC * HW;
    float* __restrict__ obase = out + (size_t)bC * (C * HW) + pC;
#pragma unroll
    for (int nf = 0; nf < NNF; ++nf) {
        const int o = nf * 16 + r;
        const float a  = s_ab[2*o];
        const float b2 = s_ab[2*o + 1];
        f32x4 v;
#pragma unroll
        for (int j = 0; j < 4; ++j) v[j] = fmaf(acc[nf][j], a, b2);
        *(f32x4*)(obase + (size_t)o * HW) = v;
    }
}

// ================================================================ fallback path (round-1, proven)
__global__ __launch_bounds__(256, 2) void gemm_kernel_fb(
    const float* __restrict__ x159, const float* __restrict__ gate,
    const short* __restrict__ wbf, float* __restrict__ out)
{
    const int lane = threadIdx.x & 63;
    const int wid  = threadIdx.x >> 6;
    const int m0   = blockIdx.x * 64 + wid * 16;
    const int mA = m0 + (lane & 15);
    const int bA = mA / HW;
    const int pA = mA - bA * HW;
    const float* __restrict__ xrow = x159 + (size_t)bA * (C * HW) + pA;
    const float* __restrict__ grow = gate + bA * C;
    const int kg = lane >> 4;

    f32x4 acc[NNF];
#pragma unroll
    for (int i = 0; i < NNF; ++i) acc[i] = f32x4{0.f, 0.f, 0.f, 0.f};
    for (int kc = 0; kc < NKC; ++kc) {
        const int cbase = kc * 32 + kg * 8;
        bf16x8 afrag;
#pragma unroll
        for (int j = 0; j < 8; ++j) {
            const int c = cbase + j;
            float v = 0.f;
            if (c < C) v = xrow[(size_t)c * HW] * grow[c];
            afrag[j] = f2bf(v);
        }
        const short* __restrict__ wb = wbf + (size_t)kc * NNF * 512 + lane * 8;
#pragma unroll
        for (int nf = 0; nf < NNF; ++nf) {
            const bf16x8 bfrag = *(const bf16x8*)(wb + (size_t)nf * 512);
            acc[nf] = __builtin_amdgcn_mfma_f32_16x16x32_bf16(afrag, bfrag, acc[nf], 0, 0, 0);
        }
    }
    const int mC = m0 + kg * 4;
    const int bC = mC / HW;
    const int pC = mC - bC * HW;
    float* __restrict__ obase = out + (size_t)bC * (C * HW) + pC;
    const int oc = lane & 15;
#pragma unroll
    for (int nf = 0; nf < NNF; ++nf)
        *(f32x4*)(obase + (size_t)(nf * 16 + oc) * HW) = acc[nf];
}

__global__ void stats_partial_fb(const float* __restrict__ x166, float* __restrict__ part) {
    const int o = blockIdx.x >> 3;
    const int bg = blockIdx.x & 7;
    float s = 0.f, q = 0.f;
    for (int i = threadIdx.x; i < 32 * HW; i += 256) {
        const int bl = i / HW;
        const int p = i - bl * HW;
        const int b = (bg << 5) + bl;
        const float v = x166[((size_t)b * C + o) * HW + p];
        s += v; q += v * v;
    }
    __shared__ float rs[256], rq[256];
    rs[threadIdx.x] = s; rq[threadIdx.x] = q;
    __syncthreads();
    for (int st = 128; st > 0; st >>= 1) {
        if (threadIdx.x < st) {
            rs[threadIdx.x] += rs[threadIdx.x + st];
            rq[threadIdx.x] += rq[threadIdx.x + st];
        }
        __syncthreads();
    }
    if (threadIdx.x == 0) {
        part[blockIdx.x * 2]     = rs[0];
        part[blockIdx.x * 2 + 1] = rq[0];
    }
}

__global__ void stats_final_fb(const float* __restrict__ part,
                               const float* __restrict__ gamma, const float* __restrict__ beta,
                               float* __restrict__ ab)
{
    const int o = threadIdx.x;
    if (o < C) {
        float s = 0.f, q = 0.f;
        for (int bg = 0; bg < 8; ++bg) {
            s += part[(o * 8 + bg) * 2];
            q += part[(o * 8 + bg) * 2 + 1];
        }
        const float invN = 1.f / (float)(BB * HW);
        const float mean = s * invN;
        const float var = fmaxf(q * invN - mean * mean, 0.f);
        const float rstd = rsqrtf(var + 1e-5f);
        const float a = rstd * gamma[o];
        ab[o * 2] = a;
        ab[o * 2 + 1] = beta[o] - mean * a;
    }
}

__global__ void norm_kernel_fb(float* __restrict__ out, const float* __restrict__ ab) {
    const int i = blockIdx.x * 256 + threadIdx.x;
    const int base = i * 4;
    const int o = (base / HW) % C;
    const float a = ab[o * 2], b = ab[o * 2 + 1];
    f32x4 v = *(const f32x4*)(out + (size_t)base);
#pragma unroll
    for (int j = 0; j < 4; ++j) v[j] = fmaf(v[j], a, b);
    *(f32x4*)(out + (size_t)base) = v;
}

// ---------------------------------------------------------------- launch
extern "C" void kernel_launch(void* const* d_in, const int* in_sizes, int n_in,
                              void* d_out, int out_size, void* d_ws, size_t ws_size,
                              hipStream_t stream)
{
    const float* x160  = (const float*)d_in[0];
    const float* x159  = (const float*)d_in[1];
    const float* w51   = (const float*)d_in[2];
    const float* b51   = (const float*)d_in[3];
    const float* w52   = (const float*)d_in[4];
    const float* b52   = (const float*)d_in[5];
    const float* w53   = (const float*)d_in[6];
    const float* gamma = (const float*)d_in[7];
    const float* beta  = (const float*)d_in[8];
    float* out = (float*)d_out;

    char* ws = (char*)d_ws;
    float* gate = (float*)ws;                    // 344,064 B
    short* wbf  = (short*)(ws + 344064);         // 236,544 B -> 580,608

    hipLaunchKernelGGL(prep_w,      dim3(231), dim3(64),  0, stream, w53, wbf);
    hipLaunchKernelGGL(gate_kernel, dim3(BB),  dim3(384), 0, stream, x160, w51, b51, w52, b52, gate);

    const size_t AB_OFF    = 580608;             // 2,688 B  -> 583,296
    const size_t PART_OFF  = 583296;             // 2,107,392 B -> 2,690,688
    const size_t APACK_OFF = 2690688;            // 35,323,904 B -> 38,014,592
    if (ws_size >= APACK_OFF + (size_t)3136 * NKC * 512 * 2) {
        // fast path: pack once, GEMM twice, no x166 materialization
        float* ab    = (float*)(ws + AB_OFF);
        float* part  = (float*)(ws + PART_OFF);
        short* apack = (short*)(ws + APACK_OFF);
        hipLaunchKernelGGL(pack_kernel,   dim3(NBLK), dim3(256), 0, stream, x159, gate, apack);
        hipLaunchKernelGGL(gemm_stats,    dim3(NBLK), dim3(256), 0, stream, apack, wbf, part);
        hipLaunchKernelGGL(stats_final_a, dim3(C),    dim3(64),  0, stream, part, gamma, beta, ab);
        hipLaunchKernelGGL(gemm_norm,     dim3(NBLK), dim3(256), 0, stream, apack, wbf, ab, out);
    } else {
        // fallback: proven round-1 pipeline
        float* part = (float*)(ws + 580608);     // 21,504 B
        float* ab   = (float*)(ws + 602112);     // 2,688 B
        hipLaunchKernelGGL(gemm_kernel_fb,   dim3(NBLK),  dim3(256), 0, stream, x159, gate, wbf, out);
        hipLaunchKernelGGL(stats_partial_fb, dim3(C * 8), dim3(256), 0, stream, out, part);
        hipLaunchKernelGGL(stats_final_fb,   dim3(1),     dim3(384), 0, stream, part, gamma, beta, ab);
        hipLaunchKernelGGL(norm_kernel_fb,   dim3(16464), dim3(256), 0, stream, out, ab);
    }
}

// Round 4
// 124.030 us; speedup vs baseline: 1.5193x; 1.5193x over previous
//
#include <hip/hip_runtime.h>
#include <hip/hip_bf16.h>

#define C   336
#define CR  84
#define BB  256
#define HW  196           // 14*14
#define NKC 11            // K chunks of 32 (K padded to 352)
#define NNF 21            // 336/16 N fragments
#define NBLK 784          // 784 blocks x 4 waves = 3136 wave tiles of 16 rows
#define LDSW 344          // pack LDS row stride in shorts (688 B = 172 dwords, 4*odd -> b128 conflict-free)

typedef __attribute__((ext_vector_type(8))) short bf16x8;
typedef __attribute__((ext_vector_type(4))) float f32x4;

typedef __attribute__((address_space(3))) void       lds_vp;
typedef const __attribute__((address_space(1))) void gbl_vp;

__device__ __forceinline__ short f2bf(float f) {
    unsigned u = __builtin_bit_cast(unsigned, f);
    u += 0x7fffu + ((u >> 16) & 1u);   // round-to-nearest-even
    return (short)(u >> 16);
}

__device__ __forceinline__ void gload_lds16(const short* g, short* l) {
    __builtin_amdgcn_global_load_lds((gbl_vp*)g, (lds_vp*)l, 16, 0, 0);
}

// ---------------------------------------------------------------- prep w53 -> bf16 frag-linear
// frag f = kc*21+nf; wbf[(f*64 + lane)*8 + j] = bf16(w53[o][c]),
// o = nf*16 + (lane&15), c = kc*32 + (lane>>4)*8 + j  (zero pad c>=336)
__global__ void prep_w(const float* __restrict__ w53, short* __restrict__ wbf) {
    const int f = blockIdx.x;           // 0..230
    const int kc = f / NNF, nf = f - kc * NNF;
    const int lane = threadIdx.x;
    const int o = nf * 16 + (lane & 15);
    const int cb = kc * 32 + (lane >> 4) * 8;
    short* dst = wbf + ((size_t)f * 64 + lane) * 8;
#pragma unroll
    for (int j = 0; j < 8; ++j) {
        const int c = cb + j;
        dst[j] = f2bf((c < C) ? w53[o * C + c] : 0.f);
    }
}

// ---------------------------------------------------------------- SE gate (block per batch)
__global__ void gate_kernel(const float* __restrict__ x160,
                            const float* __restrict__ w51, const float* __restrict__ b51,
                            const float* __restrict__ w52, const float* __restrict__ b52,
                            float* __restrict__ gate)
{
    __shared__ float s[C];
    __shared__ float red[C];
    __shared__ float h[CR];
    const int b = blockIdx.x, t = threadIdx.x;
    if (t < C) s[t] = x160[b * C + t];
    __syncthreads();
    if (t < C) {                       // layer 1: 84 outputs x 4 threads
        const int o = t >> 2, j = t & 3;
        float a = 0.f;
        const float* wr = w51 + o * C;
        for (int c = j; c < C; c += 4) a = fmaf(wr[c], s[c], a);
        red[t] = a;
    }
    __syncthreads();
    if (t < CR) {
        float a = red[4*t] + red[4*t+1] + red[4*t+2] + red[4*t+3] + b51[t];
        h[t] = fmaxf(a, 0.f);
    }
    __syncthreads();
    if (t < C) {                       // layer 2
        float a = b52[t];
        const float* wr = w52 + t * CR;
        for (int j = 0; j < CR; ++j) a = fmaf(wr[j], h[j], a);
        gate[b * C + t] = 1.f / (1.f + expf(-a));
    }
}

// ---------------------------------------------------------------- pack A = bf16(x159*gate), frag-linear
// Block = 64 rows (4 tiles). Phase 1: coalesced loads -> LDS transpose [m_local][c].
// Phase 2: wave wq emits tile (blk*4+wq): per kc a 1KB contiguous coalesced store.
__global__ __launch_bounds__(256) void pack_kernel(
    const float* __restrict__ x159, const float* __restrict__ gate,
    short* __restrict__ apack)
{
    __shared__ short at[64 * LDSW];    // 44032 B
    const int tid  = threadIdx.x;
    const int lane = tid & 63;         // m_local in phase 1
    const int wq   = tid >> 6;         // wave id
    const int m0   = blockIdx.x * 64;

    {   // phase 1: lanes = consecutive m (coalesced), wave strides over c
        const int m = m0 + lane;
        const int b = m / HW;
        const int p = m - b * HW;
        const float* __restrict__ xb = x159 + (size_t)b * (C * HW) + p;
        const float* __restrict__ gb = gate + b * C;
        short* row = at + lane * LDSW;
        for (int c = wq; c < C; c += 4)
            row[c] = f2bf(xb[(size_t)c * HW] * gb[c]);
        row[336 + (wq << 1)]     = 0;  // zero pad cols 336..343
        row[336 + (wq << 1) + 1] = 0;
    }
    __syncthreads();

    {   // phase 2: wave wq -> tile t, frag rows wq*16 .. +15
        const int row = lane & 15;
        const int kg  = lane >> 4;
        const short* src = at + (wq * 16 + row) * LDSW;
        short* dst = apack + ((size_t)(blockIdx.x * 4 + wq) * NKC * 64 + lane) * 8;
#pragma unroll
        for (int kc = 0; kc < NKC; ++kc) {
            const int c0 = kc * 32 + kg * 8;
            bf16x8 v = {0,0,0,0,0,0,0,0};
            if (c0 < LDSW) v = *(const bf16x8*)(src + c0);   // c0==344 (kc=10,kg=3) -> zero frag
            *(bf16x8*)(dst + (size_t)kc * 512) = v;
        }
    }
}

// ---------------------------------------------------------------- GEMM core: B staged in LDS (dbuf)
// bsm: 2 x 21 frags x 512 shorts = 21504 shorts (43008 B)
__device__ __forceinline__ void gemm_core_lds(const short* __restrict__ apack,
                                              const short* __restrict__ wbf,
                                              short* bsm,
                                              int t, int lane, int wid, f32x4 acc[NNF])
{
#pragma unroll
    for (int i = 0; i < NNF; ++i) acc[i] = f32x4{0.f, 0.f, 0.f, 0.f};
    const short* ap = apack + ((size_t)t * NKC * 64 + lane) * 8;

    // prologue: stage kc=0 into buf 0
    for (int f = wid; f < NNF; f += 4)
        gload_lds16(wbf + ((size_t)(0 * NNF + f) * 64 + lane) * 8, bsm + f * 512);
    __syncthreads();

    for (int kc = 0; kc < NKC; ++kc) {
        if (kc + 1 < NKC) {            // stage next slice into other buffer
            short* nb = bsm + ((kc + 1) & 1) * (NNF * 512);
            for (int f = wid; f < NNF; f += 4)
                gload_lds16(wbf + ((size_t)((kc + 1) * NNF + f) * 64 + lane) * 8, nb + f * 512);
        }
        const bf16x8 a = *(const bf16x8*)(ap + (size_t)kc * 512);
        const short* bb = bsm + (kc & 1) * (NNF * 512) + lane * 8;
#pragma unroll
        for (int nf = 0; nf < NNF; ++nf) {
            const bf16x8 bfrag = *(const bf16x8*)(bb + (size_t)nf * 512);
            acc[nf] = __builtin_amdgcn_mfma_f32_16x16x32_bf16(a, bfrag, acc[nf], 0, 0, 0);
        }
        __syncthreads();               // drains vmcnt (global_load_lds) + lgkm before buffer swap
    }
}

// ---------------------------------------------------------------- pass 1: GEMM -> per-block channel partials
__global__ __launch_bounds__(256, 3) void gemm_stats(
    const short* __restrict__ apack, const short* __restrict__ wbf,
    float* __restrict__ part)
{
    __shared__ short bsm[2 * NNF * 512];   // 43008 B, reused as float scratch after GEMM
    const int lane = threadIdx.x & 63;
    const int wid  = threadIdx.x >> 6;
    const int t    = blockIdx.x * 4 + wid;

    f32x4 acc[NNF];
    gemm_core_lds(apack, wbf, bsm, t, lane, wid, acc);

    float* lds_s = (float*)bsm;            // [4][336]
    float* lds_q = lds_s + 4 * C;          // [4][336]  (total 10752 B < 43008)
#pragma unroll
    for (int nf = 0; nf < NNF; ++nf) {
        float s = acc[nf][0] + acc[nf][1] + acc[nf][2] + acc[nf][3];
        float q = acc[nf][0]*acc[nf][0] + acc[nf][1]*acc[nf][1]
                + acc[nf][2]*acc[nf][2] + acc[nf][3]*acc[nf][3];
        s += __shfl_xor(s, 16); q += __shfl_xor(q, 16);
        s += __shfl_xor(s, 32); q += __shfl_xor(q, 32);
        if (lane < 16) { lds_s[wid * C + nf*16 + lane] = s; lds_q[wid * C + nf*16 + lane] = q; }
    }
    __syncthreads();
    for (int i = threadIdx.x; i < C; i += 256) {
        part[(size_t)blockIdx.x * (2*C) + 2*i]     = lds_s[i] + lds_s[C+i] + lds_s[2*C+i] + lds_s[3*C+i];
        part[(size_t)blockIdx.x * (2*C) + 2*i + 1] = lds_q[i] + lds_q[C+i] + lds_q[2*C+i] + lds_q[3*C+i];
    }
}

// ---------------------------------------------------------------- fold partials -> per-channel (a,b)
__global__ void stats_final_a(const float* __restrict__ part,
                              const float* __restrict__ gamma, const float* __restrict__ beta,
                              float* __restrict__ ab)
{
    const int o = blockIdx.x;          // 0..335
    const int lane = threadIdx.x;      // 0..63
    float s = 0.f, q = 0.f;
    for (int i = lane; i < NBLK; i += 64) {
        s += part[(size_t)i * (2*C) + 2*o];
        q += part[(size_t)i * (2*C) + 2*o + 1];
    }
#pragma unroll
    for (int d = 1; d < 64; d <<= 1) { s += __shfl_xor(s, d); q += __shfl_xor(q, d); }
    if (lane == 0) {
        const float invN = 1.f / (float)(BB * HW);
        const float mean = s * invN;
        const float var  = fmaxf(q * invN - mean * mean, 0.f);
        const float rstd = rsqrtf(var + 1e-5f);
        const float a = rstd * gamma[o];
        ab[2*o]     = a;
        ab[2*o + 1] = beta[o] - mean * a;
    }
}

// ---------------------------------------------------------------- pass 2: GEMM -> normalize -> out
__global__ __launch_bounds__(256, 3) void gemm_norm(
    const short* __restrict__ apack, const short* __restrict__ wbf,
    const float* __restrict__ ab, float* __restrict__ out)
{
    __shared__ short bsm[2 * NNF * 512];   // 43008 B
    __shared__ float s_ab[2 * C];          // 2688 B
    for (int i = threadIdx.x; i < 2*C; i += 256) s_ab[i] = ab[i];
    // (prologue __syncthreads inside gemm_core_lds covers s_ab visibility)

    const int lane = threadIdx.x & 63;
    const int wid  = threadIdx.x >> 6;
    const int t    = blockIdx.x * 4 + wid;

    f32x4 acc[NNF];
    gemm_core_lds(apack, wbf, bsm, t, lane, wid, acc);

    const int r  = lane & 15;
    const int kg = lane >> 4;
    const int mC = t * 16 + kg * 4;
    const int bC = mC / HW;
    const int pC = mC - bC * HW;
    float* __restrict__ obase = out + (size_t)bC * (C * HW) + pC;
#pragma unroll
    for (int nf = 0; nf < NNF; ++nf) {
        const int o = nf * 16 + r;
        const float a  = s_ab[2*o];
        const float b2 = s_ab[2*o + 1];
        f32x4 v;
#pragma unroll
        for (int j = 0; j < 4; ++j) v[j] = fmaf(acc[nf][j], a, b2);
        *(f32x4*)(obase + (size_t)o * HW) = v;
    }
}

// ---------------------------------------------------------------- launch
extern "C" void kernel_launch(void* const* d_in, const int* in_sizes, int n_in,
                              void* d_out, int out_size, void* d_ws, size_t ws_size,
                              hipStream_t stream)
{
    const float* x160  = (const float*)d_in[0];
    const float* x159  = (const float*)d_in[1];
    const float* w51   = (const float*)d_in[2];
    const float* b51   = (const float*)d_in[3];
    const float* w52   = (const float*)d_in[4];
    const float* b52   = (const float*)d_in[5];
    const float* w53   = (const float*)d_in[6];
    const float* gamma = (const float*)d_in[7];
    const float* beta  = (const float*)d_in[8];
    float* out = (float*)d_out;

    char* ws = (char*)d_ws;
    float* gate  = (float*)ws;                   // 344,064 B
    short* wbf   = (short*)(ws + 344064);        // 236,544 B -> 580,608
    float* ab    = (float*)(ws + 580608);        //   2,688 B -> 583,296
    float* part  = (float*)(ws + 583296);        // 2,107,392 B -> 2,690,688
    short* apack = (short*)(ws + 2690688);       // 35,323,904 B (verified to fit in round 3)

    hipLaunchKernelGGL(prep_w,        dim3(231),  dim3(64),  0, stream, w53, wbf);
    hipLaunchKernelGGL(gate_kernel,   dim3(BB),   dim3(384), 0, stream, x160, w51, b51, w52, b52, gate);
    hipLaunchKernelGGL(pack_kernel,   dim3(NBLK), dim3(256), 0, stream, x159, gate, apack);
    hipLaunchKernelGGL(gemm_stats,    dim3(NBLK), dim3(256), 0, stream, apack, wbf, part);
    hipLaunchKernelGGL(stats_final_a, dim3(C),    dim3(64),  0, stream, part, gamma, beta, ab);
    hipLaunchKernelGGL(gemm_norm,     dim3(NBLK), dim3(256), 0, stream, apack, wbf, ab, out);
}

// Round 5
// 120.981 us; speedup vs baseline: 1.5576x; 1.0252x over previous
//
#include <hip/hip_runtime.h>
#include <hip/hip_bf16.h>

#define C   336
#define CR  84
#define BB  256
#define HW  196           // 14*14
#define NKC 11            // K chunks of 32 (K padded to 352)
#define NNF 21            // 336/16 N fragments (real)
#define NFP 24            // padded N fragments per chunk (uniform 6 loads/wave)
#define BUFS (NFP*512)    // shorts per LDS B buffer
#define NBLK 784          // 784 blocks x 4 waves = 3136 wave tiles of 16 rows
#define LDSW 344          // pack LDS row stride in shorts

typedef __attribute__((ext_vector_type(8))) short bf16x8;
typedef __attribute__((ext_vector_type(4))) float f32x4;

typedef __attribute__((address_space(3))) void       lds_vp;
typedef const __attribute__((address_space(1))) void gbl_vp;

__device__ __forceinline__ short f2bf(float f) {
    unsigned u = __builtin_bit_cast(unsigned, f);
    u += 0x7fffu + ((u >> 16) & 1u);   // round-to-nearest-even
    return (short)(u >> 16);
}

__device__ __forceinline__ void gload_lds16(const short* g, short* l) {
    __builtin_amdgcn_global_load_lds((gbl_vp*)g, (lds_vp*)l, 16, 0, 0);
}

// ---------------------------------------------------------------- prep w53 -> bf16 frag-linear (padded to 24 frags/kc)
// wbf[((kc*NFP+ff)*64 + lane)*8 + j] = bf16(w53[o][c]), o = ff*16+(lane&15), c = kc*32+(lane>>4)*8+j
__global__ void prep_w(const float* __restrict__ w53, short* __restrict__ wbf) {
    const int f = blockIdx.x;           // 0..263
    const int kc = f / NFP, ff = f - kc * NFP;
    const int lane = threadIdx.x;
    const int o = ff * 16 + (lane & 15);
    const int cb = kc * 32 + (lane >> 4) * 8;
    short* dst = wbf + ((size_t)f * 64 + lane) * 8;
#pragma unroll
    for (int j = 0; j < 8; ++j) {
        const int c = cb + j;
        dst[j] = (ff < NNF && c < C) ? f2bf(w53[o * C + c]) : (short)0;
    }
}

// ---------------------------------------------------------------- SE gate (block per batch)
__global__ void gate_kernel(const float* __restrict__ x160,
                            const float* __restrict__ w51, const float* __restrict__ b51,
                            const float* __restrict__ w52, const float* __restrict__ b52,
                            float* __restrict__ gate)
{
    __shared__ float s[C];
    __shared__ float red[C];
    __shared__ float h[CR];
    const int b = blockIdx.x, t = threadIdx.x;
    if (t < C) s[t] = x160[b * C + t];
    __syncthreads();
    if (t < C) {                       // layer 1: 84 outputs x 4 threads
        const int o = t >> 2, j = t & 3;
        float a = 0.f;
        const float* wr = w51 + o * C;
        for (int c = j; c < C; c += 4) a = fmaf(wr[c], s[c], a);
        red[t] = a;
    }
    __syncthreads();
    if (t < CR) {
        float a = red[4*t] + red[4*t+1] + red[4*t+2] + red[4*t+3] + b51[t];
        h[t] = fmaxf(a, 0.f);
    }
    __syncthreads();
    if (t < C) {                       // layer 2
        float a = b52[t];
        const float* wr = w52 + t * CR;
        for (int j = 0; j < CR; ++j) a = fmaf(wr[j], h[j], a);
        gate[b * C + t] = 1.f / (1.f + expf(-a));
    }
}

// ---------------------------------------------------------------- pack A = bf16(x159*gate), frag-linear
__global__ __launch_bounds__(256) void pack_kernel(
    const float* __restrict__ x159, const float* __restrict__ gate,
    short* __restrict__ apack)
{
    __shared__ short at[64 * LDSW];    // 44032 B
    const int tid  = threadIdx.x;
    const int lane = tid & 63;
    const int wq   = tid >> 6;
    const int m0   = blockIdx.x * 64;

    {   // phase 1: lanes = consecutive m (coalesced), wave strides over c
        const int m = m0 + lane;
        const int b = m / HW;
        const int p = m - b * HW;
        const float* __restrict__ xb = x159 + (size_t)b * (C * HW) + p;
        const float* __restrict__ gb = gate + b * C;
        short* row = at + lane * LDSW;
        for (int c = wq; c < C; c += 4)
            row[c] = f2bf(xb[(size_t)c * HW] * gb[c]);
        row[336 + (wq << 1)]     = 0;  // zero pad cols 336..343
        row[336 + (wq << 1) + 1] = 0;
    }
    __syncthreads();

    {   // phase 2: wave wq -> tile blk*4+wq, 1KB contiguous coalesced store per kc
        const int row = lane & 15;
        const int kg  = lane >> 4;
        const short* src = at + (wq * 16 + row) * LDSW;
        short* dst = apack + ((size_t)(blockIdx.x * 4 + wq) * NKC * 64 + lane) * 8;
#pragma unroll
        for (int kc = 0; kc < NKC; ++kc) {
            const int c0 = kc * 32 + kg * 8;
            bf16x8 v = {0,0,0,0,0,0,0,0};
            if (c0 < LDSW) v = *(const bf16x8*)(src + c0);   // c0==344 -> zero frag
            *(bf16x8*)(dst + (size_t)kc * 512) = v;
        }
    }
}

// ---------------------------------------------------------------- B slice staging: exactly 6 loads per wave
__device__ __forceinline__ void stage_slice(const short* __restrict__ wbf,
                                            short* buf, int kc, int wid, int lane)
{
#pragma unroll
    for (int i = 0; i < 6; ++i) {
        const int f = i * 4 + wid;     // 4 waves x 6 = 24 frags
        gload_lds16(wbf + ((size_t)(kc * NFP + f) * 64 + lane) * 8, buf + f * 512);
    }
}

// ---------------------------------------------------------------- GEMM core: counted-vmcnt double-buffer
__device__ __forceinline__ void gemm_core_v3(const short* __restrict__ apack,
                                             const short* __restrict__ wbf,
                                             short* bsm,
                                             int t, int lane, int wid, f32x4 acc[NNF])
{
#pragma unroll
    for (int i = 0; i < NNF; ++i) acc[i] = f32x4{0.f, 0.f, 0.f, 0.f};
    const short* ap = apack + ((size_t)t * NKC * 64 + lane) * 8;

    stage_slice(wbf, bsm,        0, wid, lane);   // 6 loads -> buf0
    stage_slice(wbf, bsm + BUFS, 1, wid, lane);   // 6 loads -> buf1
    bf16x8 aa = *(const bf16x8*)ap;

#pragma unroll
    for (int kc = 0; kc < NKC; ++kc) {
        // wait: everything except the newest 6 vmem ops (= slice kc+1) is complete
        if (kc == NKC - 1) asm volatile("s_waitcnt vmcnt(0)" ::: "memory");
        else               asm volatile("s_waitcnt vmcnt(6)" ::: "memory");
        __builtin_amdgcn_s_barrier();

        bf16x8 anext = aa;
        if (kc + 1 < NKC) anext = *(const bf16x8*)(ap + (size_t)(kc + 1) * 512);

        const short* bb = bsm + (kc & 1) * BUFS + lane * 8;
#pragma unroll
        for (int nf = 0; nf < NNF; ++nf) {
            const bf16x8 bfrag = *(const bf16x8*)(bb + (size_t)nf * 512);
            acc[nf] = __builtin_amdgcn_mfma_f32_16x16x32_bf16(aa, bfrag, acc[nf], 0, 0, 0);
        }
        aa = anext;

        if (kc + 2 < NKC) {
            // my ds_reads retired -> safe for others to overwrite after barrier; NO vmem drain
            asm volatile("s_waitcnt lgkmcnt(0)" ::: "memory");
            __builtin_amdgcn_s_barrier();
            stage_slice(wbf, bsm + (kc & 1) * BUFS, kc + 2, wid, lane);
        }
    }
    __syncthreads();   // final full drain before LDS reuse / epilogue
}

// ---------------------------------------------------------------- pass 1: GEMM -> per-block channel partials
__global__ __launch_bounds__(256, 3) void gemm_stats(
    const short* __restrict__ apack, const short* __restrict__ wbf,
    float* __restrict__ part)
{
    __shared__ short bsm[2 * BUFS];        // 49152 B (reused as float scratch after GEMM)
    const int lane = threadIdx.x & 63;
    const int wid  = threadIdx.x >> 6;
    const int t    = blockIdx.x * 4 + wid;

    f32x4 acc[NNF];
    gemm_core_v3(apack, wbf, bsm, t, lane, wid, acc);

    float* lds_s = (float*)bsm;            // [4][336]
    float* lds_q = lds_s + 4 * C;          // [4][336] (10752 B < 49152)
#pragma unroll
    for (int nf = 0; nf < NNF; ++nf) {
        float s = acc[nf][0] + acc[nf][1] + acc[nf][2] + acc[nf][3];
        float q = acc[nf][0]*acc[nf][0] + acc[nf][1]*acc[nf][1]
                + acc[nf][2]*acc[nf][2] + acc[nf][3]*acc[nf][3];
        s += __shfl_xor(s, 16); q += __shfl_xor(q, 16);
        s += __shfl_xor(s, 32); q += __shfl_xor(q, 32);
        if (lane < 16) { lds_s[wid * C + nf*16 + lane] = s; lds_q[wid * C + nf*16 + lane] = q; }
    }
    __syncthreads();
    for (int i = threadIdx.x; i < C; i += 256) {
        part[(size_t)blockIdx.x * (2*C) + 2*i]     = lds_s[i] + lds_s[C+i] + lds_s[2*C+i] + lds_s[3*C+i];
        part[(size_t)blockIdx.x * (2*C) + 2*i + 1] = lds_q[i] + lds_q[C+i] + lds_q[2*C+i] + lds_q[3*C+i];
    }
}

// ---------------------------------------------------------------- fold partials -> per-channel (a,b)
__global__ void stats_final_a(const float* __restrict__ part,
                              const float* __restrict__ gamma, const float* __restrict__ beta,
                              float* __restrict__ ab)
{
    const int o = blockIdx.x;          // 0..335
    const int lane = threadIdx.x;      // 0..63
    float s = 0.f, q = 0.f;
    for (int i = lane; i < NBLK; i += 64) {
        s += part[(size_t)i * (2*C) + 2*o];
        q += part[(size_t)i * (2*C) + 2*o + 1];
    }
#pragma unroll
    for (int d = 1; d < 64; d <<= 1) { s += __shfl_xor(s, d); q += __shfl_xor(q, d); }
    if (lane == 0) {
        const float invN = 1.f / (float)(BB * HW);
        const float mean = s * invN;
        const float var  = fmaxf(q * invN - mean * mean, 0.f);
        const float rstd = rsqrtf(var + 1e-5f);
        const float a = rstd * gamma[o];
        ab[2*o]     = a;
        ab[2*o + 1] = beta[o] - mean * a;
    }
}

// ---------------------------------------------------------------- pass 2: GEMM -> normalize -> out
__global__ __launch_bounds__(256, 3) void gemm_norm(
    const short* __restrict__ apack, const short* __restrict__ wbf,
    const float* __restrict__ ab, float* __restrict__ out)
{
    __shared__ short bsm[2 * BUFS];        // 49152 B
    __shared__ float s_ab[2 * C];          // 2688 B
    for (int i = threadIdx.x; i < 2*C; i += 256) s_ab[i] = ab[i];

    const int lane = threadIdx.x & 63;
    const int wid  = threadIdx.x >> 6;
    const int t    = blockIdx.x * 4 + wid;

    f32x4 acc[NNF];
    gemm_core_v3(apack, wbf, bsm, t, lane, wid, acc);

    const int r  = lane & 15;
    const int kg = lane >> 4;
    const int mC = t * 16 + kg * 4;
    const int bC = mC / HW;
    const int pC = mC - bC * HW;
    float* __restrict__ obase = out + (size_t)bC * (C * HW) + pC;
#pragma unroll
    for (int nf = 0; nf < NNF; ++nf) {
        const int o = nf * 16 + r;
        const float a  = s_ab[2*o];
        const float b2 = s_ab[2*o + 1];
        f32x4 v;
#pragma unroll
        for (int j = 0; j < 4; ++j) v[j] = fmaf(acc[nf][j], a, b2);
        *(f32x4*)(obase + (size_t)o * HW) = v;
    }
}

// ---------------------------------------------------------------- launch
extern "C" void kernel_launch(void* const* d_in, const int* in_sizes, int n_in,
                              void* d_out, int out_size, void* d_ws, size_t ws_size,
                              hipStream_t stream)
{
    const float* x160  = (const float*)d_in[0];
    const float* x159  = (const float*)d_in[1];
    const float* w51   = (const float*)d_in[2];
    const float* b51   = (const float*)d_in[3];
    const float* w52   = (const float*)d_in[4];
    const float* b52   = (const float*)d_in[5];
    const float* w53   = (const float*)d_in[6];
    const float* gamma = (const float*)d_in[7];
    const float* beta  = (const float*)d_in[8];
    float* out = (float*)d_out;

    // ws layout (37.7 MB total; gate aliases the front of part — gate is dead
    // before gemm_stats writes part):
    char* ws = (char*)d_ws;
    short* wbf   = (short*)ws;                   // 264*64*8*2       = 270,336 B
    float* ab    = (float*)(ws + 270336);        // 672*4            =   2,688 B -> 273,024
    float* part  = (float*)(ws + 273024);        // 784*672*4        = 2,107,392 -> 2,380,416
    float* gate  = (float*)(ws + 273024);        // 344,064 B (alias over part)
    short* apack = (short*)(ws + 2380416);       // 3136*11*512*2    = 35,323,904 -> 37,704,320

    hipLaunchKernelGGL(prep_w,        dim3(11*NFP), dim3(64),  0, stream, w53, wbf);
    hipLaunchKernelGGL(gate_kernel,   dim3(BB),     dim3(384), 0, stream, x160, w51, b51, w52, b52, gate);
    hipLaunchKernelGGL(pack_kernel,   dim3(NBLK),   dim3(256), 0, stream, x159, gate, apack);
    hipLaunchKernelGGL(gemm_stats,    dim3(NBLK),   dim3(256), 0, stream, apack, wbf, part);
    hipLaunchKernelGGL(stats_final_a, dim3(C),      dim3(64),  0, stream, part, gamma, beta, ab);
    hipLaunchKernelGGL(gemm_norm,     dim3(NBLK),   dim3(256), 0, stream, apack, wbf, ab, out);
}

// Round 6
// 107.135 us; speedup vs baseline: 1.7589x; 1.1292x over previous
//
#include <hip/hip_runtime.h>
#include <hip/hip_bf16.h>

#define C   336
#define CR  84
#define BB  256
#define HW  196           // 14*14
#define NKC 11            // K chunks of 32 (K padded to 352)
#define NNF 21            // 336/16 N fragments (real)
#define NFP 24            // padded N fragments per chunk (uniform 6 stage loads/wave)
#define BUFS (NFP*512)    // shorts per LDS B buffer
#define GBLK 392          // gemm grid: 392 blocks x 4 waves x 2 tiles = 3136 tiles
#define PBLK 1568         // pack grid: 1568 blocks x 2 waves, 32 rows each
#define LDSW 344          // pack LDS row stride in shorts

typedef __attribute__((ext_vector_type(8))) short bf16x8;
typedef __attribute__((ext_vector_type(4))) float f32x4;

typedef __attribute__((address_space(3))) void       lds_vp;
typedef const __attribute__((address_space(1))) void gbl_vp;

__device__ __forceinline__ short f2bf(float f) {
    unsigned u = __builtin_bit_cast(unsigned, f);
    u += 0x7fffu + ((u >> 16) & 1u);   // round-to-nearest-even
    return (short)(u >> 16);
}

__device__ __forceinline__ void gload_lds16(const short* g, short* l) {
    __builtin_amdgcn_global_load_lds((gbl_vp*)g, (lds_vp*)l, 16, 0, 0);
}

// ---------------------------------------------------------------- prep w53 -> bf16 frag-linear (24 frags/kc)
__global__ void prep_w(const float* __restrict__ w53, short* __restrict__ wbf) {
    const int f = blockIdx.x;           // 0..263
    const int kc = f / NFP, ff = f - kc * NFP;
    const int lane = threadIdx.x;
    const int o = ff * 16 + (lane & 15);
    const int cb = kc * 32 + (lane >> 4) * 8;
    short* dst = wbf + ((size_t)f * 64 + lane) * 8;
#pragma unroll
    for (int j = 0; j < 8; ++j) {
        const int c = cb + j;
        dst[j] = (ff < NNF && c < C) ? f2bf(w53[o * C + c]) : (short)0;
    }
}

// ---------------------------------------------------------------- SE gate (block per batch)
__global__ void gate_kernel(const float* __restrict__ x160,
                            const float* __restrict__ w51, const float* __restrict__ b51,
                            const float* __restrict__ w52, const float* __restrict__ b52,
                            float* __restrict__ gate)
{
    __shared__ float s[C];
    __shared__ float red[C];
    __shared__ float h[CR];
    const int b = blockIdx.x, t = threadIdx.x;
    if (t < C) s[t] = x160[b * C + t];
    __syncthreads();
    if (t < C) {                       // layer 1: 84 outputs x 4 threads
        const int o = t >> 2, j = t & 3;
        float a = 0.f;
        const float* wr = w51 + o * C;
        for (int c = j; c < C; c += 4) a = fmaf(wr[c], s[c], a);
        red[t] = a;
    }
    __syncthreads();
    if (t < CR) {
        float a = red[4*t] + red[4*t+1] + red[4*t+2] + red[4*t+3] + b51[t];
        h[t] = fmaxf(a, 0.f);
    }
    __syncthreads();
    if (t < C) {                       // layer 2
        float a = b52[t];
        const float* wr = w52 + t * CR;
        for (int j = 0; j < CR; ++j) a = fmaf(wr[j], h[j], a);
        gate[b * C + t] = 1.f / (1.f + expf(-a));
    }
}

// ---------------------------------------------------------------- pack A = bf16(x159*gate), frag-linear
// 128-thread blocks, 32 rows each (LDS 22 KB -> 7 blocks/CU, no tail round).
__global__ __launch_bounds__(128) void pack_kernel(
    const float* __restrict__ x159, const float* __restrict__ gate,
    short* __restrict__ apack)
{
    __shared__ short at[32 * LDSW];    // 22016 B
    const int tid  = threadIdx.x;
    const int lane = tid & 63;
    const int wq   = tid >> 6;         // 0..1
    const int m0   = blockIdx.x * 32;

    {   // phase 1: 64 lanes = 32 consecutive m x 2 c (coalesced 128B segments)
        const int ml = lane & 31;
        const int ch = lane >> 5;      // 0..1
        const int m = m0 + ml;
        const int b = m / HW;
        const int p = m - b * HW;
        const float* __restrict__ xb = x159 + (size_t)b * (C * HW) + p;
        const float* __restrict__ gb = gate + b * C;
        short* row = at + ml * LDSW;
        for (int c = wq * 2 + ch; c < C; c += 4)
            row[c] = f2bf(xb[(size_t)c * HW] * gb[c]);
        const int z = 336 + (wq * 2 + ch) * 2;    // zero pad cols 336..343
        row[z] = 0; row[z + 1] = 0;
    }
    __syncthreads();

    {   // phase 2: wave wq -> tile blk*2+wq, 1KB contiguous coalesced store per kc
        const int row = lane & 15;
        const int kg  = lane >> 4;
        const short* src = at + ((wq & 1) * 16 + row) * LDSW;
        short* dst = apack + ((size_t)(blockIdx.x * 2 + wq) * NKC * 64 + lane) * 8;
#pragma unroll
        for (int kc = 0; kc < NKC; ++kc) {
            const int c0 = kc * 32 + kg * 8;
            bf16x8 v = {0,0,0,0,0,0,0,0};
            if (c0 < LDSW) v = *(const bf16x8*)(src + c0);   // c0==344 -> zero frag
            *(bf16x8*)(dst + (size_t)kc * 512) = v;
        }
    }
}

// ---------------------------------------------------------------- B slice staging: exactly 6 loads per wave
__device__ __forceinline__ void stage_slice(const short* __restrict__ wbf,
                                            short* buf, int kc, int wid, int lane)
{
#pragma unroll
    for (int i = 0; i < 6; ++i) {
        const int f = i * 4 + wid;     // 4 waves x 6 = 24 frags
        gload_lds16(wbf + ((size_t)(kc * NFP + f) * 64 + lane) * 8, buf + f * 512);
    }
}

// ---------------------------------------------------------------- GEMM core: 2 M-tiles/wave, counted vmcnt
__device__ __forceinline__ void gemm_core_v4(const short* __restrict__ apack,
                                             const short* __restrict__ wbf,
                                             short* bsm,
                                             int t0, int lane, int wid,
                                             f32x4 acc0[NNF], f32x4 acc1[NNF])
{
#pragma unroll
    for (int i = 0; i < NNF; ++i) { acc0[i] = f32x4{0.f,0.f,0.f,0.f}; acc1[i] = f32x4{0.f,0.f,0.f,0.f}; }
    const short* ap0 = apack + ((size_t)t0 * NKC * 64 + lane) * 8;
    const short* ap1 = ap0 + NKC * 512;

    stage_slice(wbf, bsm,        0, wid, lane);   // 6 -> buf0
    stage_slice(wbf, bsm + BUFS, 1, wid, lane);   // 6 -> buf1
    bf16x8 a0 = *(const bf16x8*)ap0;
    bf16x8 a1 = *(const bf16x8*)ap1;

#pragma unroll
    for (int kc = 0; kc < NKC; ++kc) {
        // steady state: newest 8 in flight = 2 A-prefetch + 6 stage(kc+1); everything older done
        if (kc == NKC - 1) asm volatile("s_waitcnt vmcnt(0)" ::: "memory");
        else               asm volatile("s_waitcnt vmcnt(8)" ::: "memory");
        __builtin_amdgcn_s_barrier();

        bf16x8 n0 = a0, n1 = a1;
        if (kc + 1 < NKC) {
            n0 = *(const bf16x8*)(ap0 + (size_t)(kc + 1) * 512);
            n1 = *(const bf16x8*)(ap1 + (size_t)(kc + 1) * 512);
        }

        const short* bb = bsm + (kc & 1) * BUFS + lane * 8;
#pragma unroll
        for (int nf = 0; nf < NNF; ++nf) {
            const bf16x8 bfrag = *(const bf16x8*)(bb + (size_t)nf * 512);
            acc0[nf] = __builtin_amdgcn_mfma_f32_16x16x32_bf16(a0, bfrag, acc0[nf], 0, 0, 0);
            acc1[nf] = __builtin_amdgcn_mfma_f32_16x16x32_bf16(a1, bfrag, acc1[nf], 0, 0, 0);
        }
        a0 = n0; a1 = n1;

        if (kc + 2 < NKC) {
            // my ds_reads retired; barrier, then overwrite the just-consumed buffer. NO vmem drain.
            asm volatile("s_waitcnt lgkmcnt(0)" ::: "memory");
            __builtin_amdgcn_s_barrier();
            stage_slice(wbf, bsm + (kc & 1) * BUFS, kc + 2, wid, lane);
        }
    }
    __syncthreads();   // full drain before LDS reuse / epilogue
}

// ---------------------------------------------------------------- pass 1: GEMM -> per-block channel partials
__global__ __launch_bounds__(256, 2) void gemm_stats(
    const short* __restrict__ apack, const short* __restrict__ wbf,
    float* __restrict__ part)
{
    __shared__ short bsm[2 * BUFS];        // 49152 B (reused as float scratch after GEMM)
    const int lane = threadIdx.x & 63;
    const int wid  = threadIdx.x >> 6;
    const int t0   = blockIdx.x * 8 + wid * 2;

    f32x4 acc0[NNF], acc1[NNF];
    gemm_core_v4(apack, wbf, bsm, t0, lane, wid, acc0, acc1);

    float* lds_s = (float*)bsm;            // [4][336]
    float* lds_q = lds_s + 4 * C;          // [4][336] (10752 B < 49152)
#pragma unroll
    for (int nf = 0; nf < NNF; ++nf) {
        float s = 0.f, q = 0.f;
#pragma unroll
        for (int j = 0; j < 4; ++j) {
            s += acc0[nf][j] + acc1[nf][j];
            q += acc0[nf][j]*acc0[nf][j] + acc1[nf][j]*acc1[nf][j];
        }
        s += __shfl_xor(s, 16); q += __shfl_xor(q, 16);
        s += __shfl_xor(s, 32); q += __shfl_xor(q, 32);
        if (lane < 16) { lds_s[wid * C + nf*16 + lane] = s; lds_q[wid * C + nf*16 + lane] = q; }
    }
    __syncthreads();
    for (int i = threadIdx.x; i < C; i += 256) {
        part[(size_t)blockIdx.x * (2*C) + 2*i]     = lds_s[i] + lds_s[C+i] + lds_s[2*C+i] + lds_s[3*C+i];
        part[(size_t)blockIdx.x * (2*C) + 2*i + 1] = lds_q[i] + lds_q[C+i] + lds_q[2*C+i] + lds_q[3*C+i];
    }
}

// ---------------------------------------------------------------- fold partials -> per-channel (a,b)
__global__ void stats_final_a(const float* __restrict__ part,
                              const float* __restrict__ gamma, const float* __restrict__ beta,
                              float* __restrict__ ab)
{
    const int o = blockIdx.x;          // 0..335
    const int lane = threadIdx.x;      // 0..63
    float s = 0.f, q = 0.f;
    for (int i = lane; i < GBLK; i += 64) {
        s += part[(size_t)i * (2*C) + 2*o];
        q += part[(size_t)i * (2*C) + 2*o + 1];
    }
#pragma unroll
    for (int d = 1; d < 64; d <<= 1) { s += __shfl_xor(s, d); q += __shfl_xor(q, d); }
    if (lane == 0) {
        const float invN = 1.f / (float)(BB * HW);
        const float mean = s * invN;
        const float var  = fmaxf(q * invN - mean * mean, 0.f);
        const float rstd = rsqrtf(var + 1e-5f);
        const float a = rstd * gamma[o];
        ab[2*o]     = a;
        ab[2*o + 1] = beta[o] - mean * a;
    }
}

// ---------------------------------------------------------------- pass 2: GEMM -> normalize -> out
__global__ __launch_bounds__(256, 2) void gemm_norm(
    const short* __restrict__ apack, const short* __restrict__ wbf,
    const float* __restrict__ ab, float* __restrict__ out)
{
    __shared__ short bsm[2 * BUFS];        // 49152 B
    __shared__ float s_ab[2 * C];          // 2688 B
    for (int i = threadIdx.x; i < 2*C; i += 256) s_ab[i] = ab[i];

    const int lane = threadIdx.x & 63;
    const int wid  = threadIdx.x >> 6;
    const int t0   = blockIdx.x * 8 + wid * 2;

    f32x4 acc0[NNF], acc1[NNF];
    gemm_core_v4(apack, wbf, bsm, t0, lane, wid, acc0, acc1);

    const int r  = lane & 15;
    const int kg = lane >> 4;
#pragma unroll
    for (int u = 0; u < 2; ++u) {
        const int mC = (t0 + u) * 16 + kg * 4;
        const int bC = mC / HW;
        const int pC = mC - bC * HW;
        float* __restrict__ obase = out + (size_t)bC * (C * HW) + pC;
#pragma unroll
        for (int nf = 0; nf < NNF; ++nf) {
            const int o = nf * 16 + r;
            const float a  = s_ab[2*o];
            const float b2 = s_ab[2*o + 1];
            const f32x4* accs = u ? acc1 : acc0;
            f32x4 v;
#pragma unroll
            for (int j = 0; j < 4; ++j) v[j] = fmaf(accs[nf][j], a, b2);
            *(f32x4*)(obase + (size_t)o * HW) = v;
        }
    }
}

// ---------------------------------------------------------------- launch
extern "C" void kernel_launch(void* const* d_in, const int* in_sizes, int n_in,
                              void* d_out, int out_size, void* d_ws, size_t ws_size,
                              hipStream_t stream)
{
    const float* x160  = (const float*)d_in[0];
    const float* x159  = (const float*)d_in[1];
    const float* w51   = (const float*)d_in[2];
    const float* b51   = (const float*)d_in[3];
    const float* w52   = (const float*)d_in[4];
    const float* b52   = (const float*)d_in[5];
    const float* w53   = (const float*)d_in[6];
    const float* gamma = (const float*)d_in[7];
    const float* beta  = (const float*)d_in[8];
    float* out = (float*)d_out;

    // ws layout (37.7 MB; gate aliases part — gate is dead before part is written)
    char* ws = (char*)d_ws;
    short* wbf   = (short*)ws;                   // 270,336 B
    float* ab    = (float*)(ws + 270336);        //   2,688 B -> 273,024
    float* part  = (float*)(ws + 273024);        // 392*672*4 = 1,053,696 -> 1,326,720
    float* gate  = (float*)(ws + 273024);        // 344,064 B (alias over part)
    short* apack = (short*)(ws + 1326720);       // 35,323,904 -> 36,650,624

    hipLaunchKernelGGL(prep_w,        dim3(11*NFP), dim3(64),  0, stream, w53, wbf);
    hipLaunchKernelGGL(gate_kernel,   dim3(BB),     dim3(384), 0, stream, x160, w51, b51, w52, b52, gate);
    hipLaunchKernelGGL(pack_kernel,   dim3(PBLK),   dim3(128), 0, stream, x159, gate, apack);
    hipLaunchKernelGGL(gemm_stats,    dim3(GBLK),   dim3(256), 0, stream, apack, wbf, part);
    hipLaunchKernelGGL(stats_final_a, dim3(C),      dim3(64),  0, stream, part, gamma, beta, ab);
    hipLaunchKernelGGL(gemm_norm,     dim3(GBLK),   dim3(256), 0, stream, apack, wbf, ab, out);
}